// Round 5
// baseline (208.678 us; speedup 1.0000x reference)
//
#include <hip/hip_runtime.h>

namespace {
constexpr int IW = 512;
constexpr int IH = 512;
constexpr int ID = 64;
constexpr int PS = IH * IW;                      // plane stride (floats)
constexpr float W_Z  = 0.5f;                     // CONTIZ^2
constexpr float W_XY = 2.0f;
constexpr float W_XZ = 1.41421356237309515f;     // 2*CONTIZ = sqrt(2)

constexpr int TPB    = 256;
constexpr int NSEG   = 4;
constexpr int DSEG   = ID / NSEG;                // 16 d-steps per segment
constexpr int BLOCKS = 2 * NSEG * IH * (IW / 4) / TPB;   // 2048 = 8 blocks/CU exactly
}

__device__ __forceinline__ float4 ld4(const float* p) { return *(const float4*)p; }

__global__ __launch_bounds__(TPB, 8) void HessianReg_kernel(const float* __restrict__ img,
                                                            float* __restrict__ out) {
    // XCD swizzle: physical blocks round-robin the 8 XCDs (b%8); remap so each
    // XCD owns 256 consecutive logical blocks = one full (n,seg) slab of 512
    // rows -> all y-neighbor rows are XCD-L2-local.
    const int lblk  = (blockIdx.x & 7) * (BLOCKS / 8) + (blockIdx.x >> 3);
    const int t     = lblk * TPB + threadIdx.x;
    const int chunk = t & 127;          // float4 index within row
    const int r     = t >> 7;
    const int h     = r & (IH - 1);     // wave-uniform (r uniform per wave)
    const int q     = r >> 9;           // [0,8): one (n,seg) slab per XCD
    const int seg   = q & 3;
    const int n     = q >> 2;
    const int d0    = seg * DSEG;
    const int w0    = chunk << 2;

    const bool hasW = (w0 < IW - 4);    // per-lane: false only for chunk 127
    const bool hy2  = (h < IH - 1);     // wave-uniform
    const bool hy3  = (h < IH - 2);     // wave-uniform
    // lane 63 of a half-row wave can't shuffle its +4/+5 tail from lane+1:
    const bool seam = ((threadIdx.x & 63) == 63) && hasW;

    const float* p = img + ((size_t)((n * ID + d0) * IH + h)) * IW + w0;

    const float4 Z4 = make_float4(0.f, 0.f, 0.f, 0.f);

    // Rolling state only: A=(d,h) B=(d,h+1) E=(d+1,h). Tails come from
    // lane+1 via shuffle each step (no stored tail registers, no strided loads).
    float4 A = ld4(p);
    float4 B = Z4;
    if (hy2) B = ld4(p + IW);
    float4 E = ld4(p + PS);             // d0+1 <= 49: always valid

    float acc = 0.f;

    for (int dl = 0; dl < DSEG; ++dl) {
        const int d = d0 + dl;          // wave-uniform
        const bool gz2 = (d < ID - 1);
        const bool gz3 = (d < ID - 2);

        // ---- fresh loads first (consumed ~40 VALU instrs later)
        float4 C = Z4;                  // (d,   h+2)
        if (hy3) C = ld4(p + 2 * IW);
        float4 G = Z4;                  // (d+1, h+1)
        if (gz2 && hy2) G = ld4(p + PS + IW);
        float4 F = Z4;                  // (d+2, h)
        if (gz3) F = ld4(p + 2 * PS);

        // ---- tails from neighbor lane (chunk+1 lives in lane+1)
        float a4 = __shfl_down(A.x, 1, 64);
        float a5 = __shfl_down(A.y, 1, 64);
        float b4 = __shfl_down(B.x, 1, 64);
        float e4 = __shfl_down(E.x, 1, 64);
        if (seam) {                     // 1 active lane per wave, exec-masked loads
            a4 = p[4]; a5 = p[5];
            if (hy2) b4 = p[IW + 4];
            if (gz2) e4 = p[PS + 4];
        }

        // ---- rolled-state-only terms (no dependence on C/G/F)
        // g_xx (weight 1)
        {
            float s = fabsf(A.x - 2.f * A.y + A.z) + fabsf(A.y - 2.f * A.z + A.w);
            if (hasW) s += fabsf(A.z - 2.f * A.w + a4) + fabsf(A.w - 2.f * a4 + a5);
            acc += s;
        }
        // g_xy (weight 2)
        if (hy2) {
            float s = fabsf(A.x - A.y - B.x + B.y) + fabsf(A.y - A.z - B.y + B.z)
                    + fabsf(A.z - A.w - B.z + B.w);
            if (hasW) s += fabsf(A.w - a4 - B.w + b4);
            acc += W_XY * s;
        }
        // g_xz (weight sqrt(2))
        if (gz2) {
            float s = fabsf(A.x - A.y - E.x + E.y) + fabsf(A.y - A.z - E.y + E.z)
                    + fabsf(A.z - A.w - E.z + E.w);
            if (hasW) s += fabsf(A.w - a4 - E.w + e4);
            acc += W_XZ * s;
        }

        // ---- fresh-dependent terms
        // g_yy (weight 1)
        if (hy3)
            acc += fabsf(A.x - 2.f * B.x + C.x) + fabsf(A.y - 2.f * B.y + C.y)
                 + fabsf(A.z - 2.f * B.z + C.z) + fabsf(A.w - 2.f * B.w + C.w);
        // g_zz (weight 0.5)
        if (gz3)
            acc += W_Z * (fabsf(A.x - 2.f * E.x + F.x) + fabsf(A.y - 2.f * E.y + F.y)
                        + fabsf(A.z - 2.f * E.z + F.z) + fabsf(A.w - 2.f * E.w + F.w));
        // g_yz (weight sqrt(2))
        if (gz2 && hy2)
            acc += W_XZ * (fabsf(A.x - B.x - E.x + G.x) + fabsf(A.y - B.y - E.y + G.y)
                         + fabsf(A.z - B.z - E.z + G.z) + fabsf(A.w - B.w - E.w + G.w));

        // ---- roll z
        A = E;          // (d+1,h)   -> next A
        B = G;          // (d+1,h+1) -> next B
        E = F;          // (d+2,h)   -> next E
        p += PS;
    }

    // wave (64-lane) shuffle reduce
    for (int off = 32; off > 0; off >>= 1)
        acc += __shfl_down(acc, off, 64);

    __shared__ float ws[TPB / 64];
    const int lane = threadIdx.x & 63;
    const int wv   = threadIdx.x >> 6;
    if (lane == 0) ws[wv] = acc;
    __syncthreads();
    if (threadIdx.x == 0) {
        float bsum = 0.f;
        #pragma unroll
        for (int i = 0; i < TPB / 64; ++i) bsum += ws[i];
        atomicAdd(out, bsum * (1.0f / (IH * IW)));
    }
}

extern "C" void kernel_launch(void* const* d_in, const int* in_sizes, int n_in,
                              void* d_out, int out_size, void* d_ws, size_t ws_size,
                              hipStream_t stream) {
    const float* img = (const float*)d_in[0];
    float* out = (float*)d_out;
    // d_out is re-poisoned to 0xAA before every timed launch -> zero it on-stream.
    hipMemsetAsync(out, 0, sizeof(float), stream);
    hipLaunchKernelGGL(HessianReg_kernel, dim3(BLOCKS), dim3(TPB), 0, stream, img, out);
}

// Round 6
// 203.595 us; speedup vs baseline: 1.0250x; 1.0250x over previous
//
#include <hip/hip_runtime.h>

namespace {
constexpr int IW = 512;
constexpr int IH = 512;
constexpr int ID = 64;
constexpr int PS = IH * IW;          // plane stride (floats)
constexpr int NS = ID * PS;          // batch stride (floats)
constexpr float W_Z  = 0.5f;                     // CONTIZ^2
constexpr float W_XY = 2.0f;
constexpr float W_XZ = 1.41421356237309515f;     // 2*CONTIZ = sqrt(2)

constexpr int TPB    = 256;
constexpr int BLOCKS = ID * IH * (IW / 4) / TPB; // 16384; n handled by pairing
constexpr int NSLOT  = 64;                       // partial-sum slots in d_ws
constexpr int SLOTSTRIDE = 32;                   // floats = 128 B apart
}

__device__ __forceinline__ float4 ld4(const float* p) { return *(const float4*)p; }
__device__ __forceinline__ float2 ld2(const float* p) { return *(const float2*)p; }

struct Frag { float4 A, B, C, E, F, G; float a4, a5, b4, e4; };

__device__ __forceinline__ void loadFrag(const float* __restrict__ p, Frag& f,
                                         bool hasW, bool hy2, bool hy3,
                                         bool gz2, bool gz3) {
    const float4 Z4 = make_float4(0.f, 0.f, 0.f, 0.f);
    f.A = ld4(p);                                  // (d,   h  )
    f.a4 = 0.f; f.a5 = 0.f; f.b4 = 0.f; f.e4 = 0.f;
    if (hasW) { float2 t = ld2(p + 4); f.a4 = t.x; f.a5 = t.y; }
    f.B = Z4; if (hy2) { f.B = ld4(p + IW); if (hasW) f.b4 = p[IW + 4]; }   // (d, h+1)
    f.C = Z4; if (hy3)   f.C = ld4(p + 2 * IW);                             // (d, h+2)
    f.E = Z4; if (gz2) { f.E = ld4(p + PS); if (hasW) f.e4 = p[PS + 4]; }   // (d+1, h)
    f.F = Z4; if (gz3)   f.F = ld4(p + 2 * PS);                             // (d+2, h)
    f.G = Z4; if (gz2 && hy2) f.G = ld4(p + PS + IW);                       // (d+1, h+1)
}

__device__ __forceinline__ float stencil(const Frag& f, bool hasW, bool hy2,
                                         bool hy3, bool gz2, bool gz3) {
    float acc = 0.f;
    // g_xx (weight 1)
    {
        float s = fabsf(f.A.x - 2.f * f.A.y + f.A.z) + fabsf(f.A.y - 2.f * f.A.z + f.A.w);
        if (hasW) s += fabsf(f.A.z - 2.f * f.A.w + f.a4) + fabsf(f.A.w - 2.f * f.a4 + f.a5);
        acc += s;
    }
    // g_yy (weight 1)
    if (hy3)
        acc += fabsf(f.A.x - 2.f * f.B.x + f.C.x) + fabsf(f.A.y - 2.f * f.B.y + f.C.y)
             + fabsf(f.A.z - 2.f * f.B.z + f.C.z) + fabsf(f.A.w - 2.f * f.B.w + f.C.w);
    // g_zz (weight 0.5)
    if (gz3)
        acc += W_Z * (fabsf(f.A.x - 2.f * f.E.x + f.F.x) + fabsf(f.A.y - 2.f * f.E.y + f.F.y)
                    + fabsf(f.A.z - 2.f * f.E.z + f.F.z) + fabsf(f.A.w - 2.f * f.E.w + f.F.w));
    // g_xy (weight 2)
    if (hy2) {
        float s = fabsf(f.A.x - f.A.y - f.B.x + f.B.y) + fabsf(f.A.y - f.A.z - f.B.y + f.B.z)
                + fabsf(f.A.z - f.A.w - f.B.z + f.B.w);
        if (hasW) s += fabsf(f.A.w - f.a4 - f.B.w + f.b4);
        acc += W_XY * s;
    }
    // g_xz (weight sqrt(2))
    if (gz2) {
        float s = fabsf(f.A.x - f.A.y - f.E.x + f.E.y) + fabsf(f.A.y - f.A.z - f.E.y + f.E.z)
                + fabsf(f.A.z - f.A.w - f.E.z + f.E.w);
        if (hasW) s += fabsf(f.A.w - f.a4 - f.E.w + f.e4);
        acc += W_XZ * s;
    }
    // g_yz (weight sqrt(2))
    if (gz2 && hy2)
        acc += W_XZ * (fabsf(f.A.x - f.B.x - f.E.x + f.G.x) + fabsf(f.A.y - f.B.y - f.E.y + f.G.y)
                     + fabsf(f.A.z - f.B.z - f.E.z + f.G.z) + fabsf(f.A.w - f.B.w - f.E.w + f.G.w));
    return acc;
}

__global__ __launch_bounds__(TPB, 6) void HessianReg_kernel(const float* __restrict__ img,
                                                            float* __restrict__ ws) {
    // XCD swizzle by h-slab: physical blocks round-robin XCDs (b&7); XCD k owns
    // h in [64k, 64k+64) for ALL d (both n via in-thread pairing). Within the
    // slab, blocks walk h inner (1-block y-halo distance) and d outer (32/64-
    // block z-halo distance) -> all halos land in the same XCD's L2.
    const int hseg = blockIdx.x & 7;
    const int i    = blockIdx.x >> 3;        // 0..2047 within slab
    const int t    = i * TPB + threadIdx.x;
    const int chunk = t & 127;               // float4 index within row
    const int rr    = t >> 7;                // 0..4095: hh inner, d outer
    const int hh    = rr & 63;
    const int d     = rr >> 6;               // 0..63
    const int h     = hseg * 64 + hh;
    const int w0    = chunk << 2;

    const bool hasW = (chunk < 127);         // per-lane (1 lane/wave false)
    const bool hy2  = (h < IH - 1);          // wave-uniform
    const bool hy3  = (h < IH - 2);
    const bool gz2  = (d < ID - 1);
    const bool gz3  = (d < ID - 2);

    const float* p = img + (size_t)(d * IH + h) * IW + w0;

    // Two independent chunks (n=0, n=1): all 18 loads issued before compute.
    Frag f0, f1;
    loadFrag(p,      f0, hasW, hy2, hy3, gz2, gz3);
    loadFrag(p + NS, f1, hasW, hy2, hy3, gz2, gz3);

    float acc = stencil(f0, hasW, hy2, hy3, gz2, gz3)
              + stencil(f1, hasW, hy2, hy3, gz2, gz3);

    // wave (64-lane) shuffle reduce
    for (int off = 32; off > 0; off >>= 1)
        acc += __shfl_down(acc, off, 64);

    __shared__ float red[TPB / 64];
    const int lane = threadIdx.x & 63;
    const int wv   = threadIdx.x >> 6;
    if (lane == 0) red[wv] = acc;
    __syncthreads();
    if (threadIdx.x == 0) {
        float bsum = red[0] + red[1] + red[2] + red[3];
        // scatter across 64 slots (128 B apart) -> 256 atomics/address max
        atomicAdd(&ws[(blockIdx.x & (NSLOT - 1)) * SLOTSTRIDE], bsum);
    }
}

__global__ void HessianReg_final(const float* __restrict__ ws, float* __restrict__ out) {
    float v = ws[threadIdx.x * SLOTSTRIDE];
    for (int off = 32; off > 0; off >>= 1)
        v += __shfl_down(v, off, 64);
    if (threadIdx.x == 0) out[0] = v * (1.0f / (IH * IW));
}

extern "C" void kernel_launch(void* const* d_in, const int* in_sizes, int n_in,
                              void* d_out, int out_size, void* d_ws, size_t ws_size,
                              hipStream_t stream) {
    const float* img = (const float*)d_in[0];
    float* ws  = (float*)d_ws;
    float* out = (float*)d_out;
    // d_ws is re-poisoned to 0xAA before every timed launch -> zero the slots.
    hipMemsetAsync(ws, 0, NSLOT * SLOTSTRIDE * sizeof(float), stream);
    hipLaunchKernelGGL(HessianReg_kernel, dim3(BLOCKS), dim3(TPB), 0, stream, img, ws);
    hipLaunchKernelGGL(HessianReg_final, dim3(1), dim3(64), 0, stream, ws, out);
}